// Round 9
// baseline (436.037 us; speedup 1.0000x reference)
//
#include <hip/hip_runtime.h>
#include <hip/hip_bf16.h>
#include <math.h>

#define DIM 128
#define HID 256

typedef short s8x __attribute__((ext_vector_type(8)));   // 8 bf16 (as raw shorts)
typedef float f4x __attribute__((ext_vector_type(4)));   // MFMA accumulator

__device__ __forceinline__ unsigned short f2bf(float f) {
    unsigned int u = __float_as_uint(f);
    u += 0x7FFF + ((u >> 16) & 1);   // round-to-nearest-even
    return (unsigned short)(u >> 16);
}
__device__ __forceinline__ float bf2f(unsigned short b) {
    return __uint_as_float(((unsigned int)b) << 16);
}
__device__ __forceinline__ float bflo(unsigned int p) {   // low bf16 of packed pair
    return __uint_as_float(p << 16);
}
__device__ __forceinline__ float bfhi(unsigned int p) {   // high bf16 of packed pair
    return __uint_as_float(p & 0xffff0000u);
}

// ===========================================================================
// CSR build via bucketed counting sort — ZERO device-scope atomics (each costs
// ~64B HBM-side traffic on gfx950; measured 120us for one count pass in r2).
// Buckets: node id >> 7 (128 nodes/bucket). NBE=256 edge-chunk blocks.
//
// Session lessons pinned:
//  r2: global atomics per edge = ~64B HBM traffic each -> never per-edge.
//  r4: ffn occupancy 30->49% did NOT help (latency not residency bound).
//  r5: cross-barrier register prefetch in ffn -> scratch spills.
//  r6: merging independent latency-bound + streaming grids (hist+rot) wins.
//  r7: inverse rotation lives in gather2 epilogue (one fewer bf16 rounding).
//  r8: gather unroll x8 neutral (VGPR 52, occ 36%) -> keep x4.
//  r9 (this): degree-balanced gather via counting-sort permutation (waves get
//      equal-degree nodes; Poisson(16) max-of-4 was ~25% idle). Bit-identical
//      output (same per-node edge order), only processing order changes.
// ===========================================================================

// merged: hist blocks [0,NBE) + forward-rotation blocks [NBE,NBE+nbRot) +
// weight-cvt blocks [NBE+nbRot, NBE+nbRot+16).
__global__ __launch_bounds__(256) void hist_rot_kernel(
        const int* __restrict__ src, const int* __restrict__ dst,
        int* __restrict__ TD, int* __restrict__ TS, int nE, int nbuck, int chunk,
        int NBE,
        const float* __restrict__ x, const float* __restrict__ R,
        unsigned short* __restrict__ h0,
        const float* __restrict__ w1, const float* __restrict__ w2,
        unsigned short* __restrict__ w1b, unsigned short* __restrict__ w2b,
        int n, int nbRot) {
    __shared__ int hd[1024], hs[1024];
    const int tid = threadIdx.x, blk = blockIdx.x;

    if (blk >= NBE) {
        const int rb = blk - NBE;
        if (rb >= nbRot) {           // ---- weight conversion tail (16 blocks)
            int t = (rb - nbRot) * 256 + tid;
            for (int i = t; i < 32768; i += 4096) {
                w1b[i] = f2bf(w1[i]);
                w2b[i] = f2bf(w2[i]);
            }
            return;
        }
        // ---- forward rotation: h0 = rot(x) in bf16
        int u = rb * 256 + tid;
        if (u >= n * 8) return;
        int nd = u >> 3, b = u & 7;
        const float* xp = &x[(size_t)nd * DIM + b * 16];
        const float* Rp = &R[(size_t)nd * DIM + b * 16];
        float xv[16], rv[16];
#pragma unroll
        for (int d = 0; d < 4; ++d) {
            *(float4*)&xv[d * 4] = *(const float4*)&xp[d * 4];
            *(float4*)&rv[d * 4] = *(const float4*)&Rp[d * 4];
        }
        unsigned short ob[16];
#pragma unroll
        for (int c = 0; c < 4; ++c)
#pragma unroll
            for (int e = 0; e < 4; ++e) {
                float acc = 0.f;
#pragma unroll
                for (int d = 0; d < 4; ++d) acc += rv[c * 4 + d] * xv[d * 4 + e];
                ob[c * 4 + e] = f2bf(acc);
            }
        unsigned short* op = &h0[(size_t)nd * DIM + b * 16];
        *(s8x*)&op[0] = *(s8x*)&ob[0];
        *(s8x*)&op[8] = *(s8x*)&ob[8];
        return;
    }

    // ---- hist part: per-(block,bucket) histograms of dst and src, unroll x2
    for (int b = tid; b < nbuck; b += 256) { hd[b] = 0; hs[b] = 0; }
    __syncthreads();
    int beg = blk * chunk, end = min(beg + chunk, nE);
    int i = beg + tid;
    for (; i + 256 < end; i += 512) {
        int d0 = dst[i], d1 = dst[i + 256];
        int s0 = src[i], s1 = src[i + 256];
        atomicAdd(&hd[d0 >> 7], 1);
        atomicAdd(&hd[d1 >> 7], 1);
        atomicAdd(&hs[s0 >> 7], 1);
        atomicAdd(&hs[s1 >> 7], 1);
    }
    if (i < end) {
        atomicAdd(&hd[dst[i] >> 7], 1);
        atomicAdd(&hs[src[i] >> 7], 1);
    }
    __syncthreads();
    for (int b = tid; b < nbuck; b += 256) {   // bucket-major layout for scan
        TD[b * NBE + blk] = hd[b];
        TS[b * NBE + blk] = hs[b];
    }
}

// hierarchical exclusive scan: 1024 elems/block
__global__ void scan_blocks(const int* in, int* out, int* bsums, int n) {
    __shared__ int part[256];
    const int tid = threadIdx.x;
    const int base = blockIdx.x * 1024 + tid * 4;
    int v[4];
    int sum = 0;
#pragma unroll
    for (int k = 0; k < 4; ++k) {
        v[k] = (base + k < n) ? in[base + k] : 0;
        sum += v[k];
    }
    part[tid] = sum;
    __syncthreads();
    for (int off = 1; off < 256; off <<= 1) {
        int t = (tid >= off) ? part[tid - off] : 0;
        __syncthreads();
        part[tid] += t;
        __syncthreads();
    }
    int excl = part[tid] - sum;
    if (tid == 255) bsums[blockIdx.x] = part[255];
#pragma unroll
    for (int k = 0; k < 4; ++k) {
        if (base + k < n) out[base + k] = excl;
        excl += v[k];
    }
}

// scan of block sums, nb <= 2048, single block of 256 (8 elems/thread)
__global__ void scan_sums(int* bsums, int nb) {
    __shared__ int part[256];
    const int tid = threadIdx.x;
    const int base = tid * 8;
    int v[8];
    int sum = 0;
#pragma unroll
    for (int k = 0; k < 8; ++k) {
        v[k] = (base + k < nb) ? bsums[base + k] : 0;
        sum += v[k];
    }
    part[tid] = sum;
    __syncthreads();
    for (int off = 1; off < 256; off <<= 1) {
        int t = (tid >= off) ? part[tid - off] : 0;
        __syncthreads();
        part[tid] += t;
        __syncthreads();
    }
    int excl = part[tid] - sum;
#pragma unroll
    for (int k = 0; k < 8; ++k) {
        if (base + k < nb) bsums[base + k] = excl;
        excl += v[k];
    }
}

// add block offsets; elements [half,n2) additionally corrected by -E
// (half=n2, E=0 -> plain scan finalize, reused for the perm table)
__global__ void scan_add(int* T, const int* __restrict__ bsums, int n2, int half, int E) {
    int i = blockIdx.x * blockDim.x + threadIdx.x;
    if (i < n2) {
        int v = T[i] + bsums[i >> 10];
        T[i] = (i >= half) ? v - E : v;
    }
}

// pass 2: scatter edges into bucket-ordered arrays using LDS cursors, unroll x2
__global__ __launch_bounds__(256) void scatter_edges(
        const int* __restrict__ src, const int* __restrict__ dst,
        const int* __restrict__ TD, const int* __restrict__ TS,
        unsigned int* __restrict__ pairs, unsigned char* __restrict__ sbyte,
        int nE, int nbuck, int chunk, int NBE) {
    __shared__ int cd[1024], cs[1024];
    const int tid = threadIdx.x, blk = blockIdx.x;
    for (int b = tid; b < nbuck; b += 256) {
        cd[b] = TD[b * NBE + blk];
        cs[b] = TS[b * NBE + blk];
    }
    __syncthreads();
    int beg = blk * chunk, end = min(beg + chunk, nE);
    int i = beg + tid;
    for (; i + 256 < end; i += 512) {
        int s0 = src[i], d0 = dst[i];
        int s1 = src[i + 256], d1 = dst[i + 256];
        int pd0 = atomicAdd(&cd[d0 >> 7], 1);
        pairs[pd0] = ((unsigned)s0 << 7) | (unsigned)(d0 & 127);
        int pd1 = atomicAdd(&cd[d1 >> 7], 1);
        pairs[pd1] = ((unsigned)s1 << 7) | (unsigned)(d1 & 127);
        int ps0 = atomicAdd(&cs[s0 >> 7], 1);
        sbyte[ps0] = (unsigned char)(s0 & 127);
        int ps1 = atomicAdd(&cs[s1 >> 7], 1);
        sbyte[ps1] = (unsigned char)(s1 & 127);
    }
    if (i < end) {
        int s = src[i], d = dst[i];
        int pd = atomicAdd(&cd[d >> 7], 1);
        pairs[pd] = ((unsigned)s << 7) | (unsigned)(d & 127);
        int ps = atomicAdd(&cs[s >> 7], 1);
        sbyte[ps] = (unsigned char)(s & 127);
    }
}

// pass 3a: per src-bucket out-degree histogram -> rdeg = rsqrt(deg)
__global__ __launch_bounds__(256) void finalize_src(
        const unsigned char* __restrict__ sbyte, const int* __restrict__ TS,
        float* __restrict__ rdeg, int nE, int nbuck, int nN, int NBE) {
    __shared__ int hist[128];
    const int tid = threadIdx.x, b = blockIdx.x;
    if (tid < 128) hist[tid] = 0;
    __syncthreads();
    int beg = TS[b * NBE];
    int end = (b + 1 < nbuck) ? TS[(b + 1) * NBE] : nE;
    for (int i = beg + tid; i < end; i += 256)
        atomicAdd(&hist[sbyte[i]], 1);
    __syncthreads();
    if (tid < 128) {
        int idx = (b << 7) + tid;
        if (idx < nN) rdeg[idx] = rsqrtf((float)hist[tid]);
    }
}

// pass 3b: per dst-bucket finalize: rowstart + locally sorted (src,coef).
// Additionally emits the per-(degree-bin, bucket) count table TP for the
// degree-balancing permutation (in-degrees are already in hist[]).
template<bool PACK>
__global__ __launch_bounds__(256) void finalize_dst(
        const unsigned int* __restrict__ pairs, const int* __restrict__ TD,
        const float* __restrict__ rdeg,
        int* __restrict__ rowstart, uint2* __restrict__ ecsr,
        int* __restrict__ esrcA, int* __restrict__ TP,
        int nE, int nbuck, int nN, int NBE) {
    __shared__ int hist[128], sbuf[128], cur[128], hist2[512];
    const int tid = threadIdx.x, b = blockIdx.x;
    int beg = TD[b * NBE];
    int end = (b + 1 < nbuck) ? TD[(b + 1) * NBE] : nE;
    if (tid < 128) hist[tid] = 0;
    for (int t = tid; t < 512; t += 256) hist2[t] = 0;
    __syncthreads();
    for (int i = beg + tid; i < end; i += 256)
        atomicAdd(&hist[(int)(pairs[i] & 127u)], 1);
    __syncthreads();
    int v = (tid < 128) ? hist[tid] : 0;
    if (tid < 128) {
        sbuf[tid] = v;
        int idx = (b << 7) + tid;
        if (idx < nN) atomicAdd(&hist2[min(v, 511)], 1);   // degree-bin count
    }
    __syncthreads();
    for (int off = 1; off < 128; off <<= 1) {
        int t = (tid < 128 && tid >= off) ? sbuf[tid - off] : 0;
        __syncthreads();
        if (tid < 128) sbuf[tid] += t;
        __syncthreads();
    }
    if (tid < 128) {
        int excl = sbuf[tid] - v;
        cur[tid] = excl;
        int idx = (b << 7) + tid;
        if (idx <= nN) rowstart[idx] = beg + excl;   // covers rowstart[N]=E too
    }
    for (int t = tid; t < 512; t += 256) TP[t * nbuck + b] = hist2[t];
    __syncthreads();
    for (int i = beg + tid; i < end; i += 256) {
        unsigned int p = pairs[i];
        int l = (int)(p & 127u);
        int s = (int)(p >> 7);
        int pos = atomicAdd(&cur[l], 1);
        if (PACK) {
            float coef = rdeg[s] * rdeg[(b << 7) + l];
            ecsr[beg + pos] = make_uint2((unsigned)s, __float_as_uint(coef));
        } else {
            esrcA[beg + pos] = s;
        }
    }
}

// counting-sort scatter: perm = node ids ordered by (degree-bin, bucket)
__global__ __launch_bounds__(256) void perm_scatter(
        const int* __restrict__ rowstart, const int* __restrict__ TP,
        int* __restrict__ perm, int nbuck, int nN) {
    __shared__ int cur[512];
    const int tid = threadIdx.x, b = blockIdx.x;
    for (int t = tid; t < 512; t += 256) cur[t] = TP[t * nbuck + b];
    __syncthreads();
    if (tid < 128) {
        int v = (b << 7) + tid;
        if (v < nN) {
            int deg = rowstart[v + 1] - rowstart[v];
            int bin = min(deg, 511);
            int pos = atomicAdd(&cur[bin], 1);
            perm[pos] = v;
        }
    }
}

// ---------------------------------------------------------------------------
// gather round (bf16 rows): hdst[v] = sum_{e in row v} hsrc[esrc[e]] * coef
// 16 lanes per node (16 B dwordx4 each), 16 nodes per 256-block, unroll x4
// (x8 tried r8: neutral, worse occupancy). Nodes processed in degree-sorted
// order via perm[] so each wave's 4 nodes have near-equal degree (kills the
// Poisson max-of-4 idle). Output is bit-identical (same per-node edge order).
// Template ROT: round-2 variant applies the inverse rotation R^T per bundle
// to the fp32 accumulators before the bf16 write.
template<bool PACK, bool ROT>
__global__ __launch_bounds__(256) void gather_kernel(
        const unsigned short* __restrict__ hsrc,
        const uint2* __restrict__ ecsr, const int* __restrict__ esrcA,
        const float* __restrict__ rdeg, const int* __restrict__ rowstart,
        const float* __restrict__ R, const int* __restrict__ perm,
        unsigned short* __restrict__ hdst, int n) {
    const int gi = blockIdx.x * 16 + (threadIdx.x >> 4);
    const int lane = threadIdx.x & 15;        // owns 8 bf16 = 16 B of the row
    if (gi >= n) return;
    const int node = perm[gi];
    const int beg = rowstart[node];
    const int end = rowstart[node + 1];
    float rd = 0.f;
    if (!PACK) rd = rdeg[node];

    // issue R row load early (ROT only): lane owns floats [lane*8, lane*8+8)
    float4 r0, r1;
    if (ROT) {
        r0 = *(const float4*)&R[(size_t)node * DIM + lane * 8];
        r1 = *(const float4*)&R[(size_t)node * DIM + lane * 8 + 4];
    }

    float a0 = 0.f, a1 = 0.f, a2 = 0.f, a3 = 0.f;
    float a4 = 0.f, a5 = 0.f, a6 = 0.f, a7 = 0.f;
    int i = beg;
    for (; i + 4 <= end; i += 4) {
        int s0, s1, s2, s3;
        float c0, c1, c2, c3;
        if (PACK) {
            uint2 e0 = ecsr[i], e1 = ecsr[i + 1], e2 = ecsr[i + 2], e3 = ecsr[i + 3];
            s0 = (int)e0.x; c0 = __uint_as_float(e0.y);
            s1 = (int)e1.x; c1 = __uint_as_float(e1.y);
            s2 = (int)e2.x; c2 = __uint_as_float(e2.y);
            s3 = (int)e3.x; c3 = __uint_as_float(e3.y);
        } else {
            s0 = esrcA[i]; s1 = esrcA[i + 1]; s2 = esrcA[i + 2]; s3 = esrcA[i + 3];
            c0 = rdeg[s0] * rd; c1 = rdeg[s1] * rd;
            c2 = rdeg[s2] * rd; c3 = rdeg[s3] * rd;
        }
        uint4 p0 = *(const uint4*)&hsrc[(size_t)s0 * DIM + lane * 8];
        uint4 p1 = *(const uint4*)&hsrc[(size_t)s1 * DIM + lane * 8];
        uint4 p2 = *(const uint4*)&hsrc[(size_t)s2 * DIM + lane * 8];
        uint4 p3 = *(const uint4*)&hsrc[(size_t)s3 * DIM + lane * 8];
        a0 += bflo(p0.x) * c0 + bflo(p1.x) * c1 + bflo(p2.x) * c2 + bflo(p3.x) * c3;
        a1 += bfhi(p0.x) * c0 + bfhi(p1.x) * c1 + bfhi(p2.x) * c2 + bfhi(p3.x) * c3;
        a2 += bflo(p0.y) * c0 + bflo(p1.y) * c1 + bflo(p2.y) * c2 + bflo(p3.y) * c3;
        a3 += bfhi(p0.y) * c0 + bfhi(p1.y) * c1 + bfhi(p2.y) * c2 + bfhi(p3.y) * c3;
        a4 += bflo(p0.z) * c0 + bflo(p1.z) * c1 + bflo(p2.z) * c2 + bflo(p3.z) * c3;
        a5 += bfhi(p0.z) * c0 + bfhi(p1.z) * c1 + bfhi(p2.z) * c2 + bfhi(p3.z) * c3;
        a6 += bflo(p0.w) * c0 + bflo(p1.w) * c1 + bflo(p2.w) * c2 + bflo(p3.w) * c3;
        a7 += bfhi(p0.w) * c0 + bfhi(p1.w) * c1 + bfhi(p2.w) * c2 + bfhi(p3.w) * c3;
    }
    for (; i < end; ++i) {
        int s0;
        float c0;
        if (PACK) {
            uint2 e0 = ecsr[i];
            s0 = (int)e0.x; c0 = __uint_as_float(e0.y);
        } else {
            s0 = esrcA[i];
            c0 = rdeg[s0] * rd;
        }
        uint4 p0 = *(const uint4*)&hsrc[(size_t)s0 * DIM + lane * 8];
        a0 += bflo(p0.x) * c0;
        a1 += bfhi(p0.x) * c0;
        a2 += bflo(p0.y) * c0;
        a3 += bfhi(p0.y) * c0;
        a4 += bflo(p0.z) * c0;
        a5 += bfhi(p0.z) * c0;
        a6 += bflo(p0.w) * c0;
        a7 += bfhi(p0.w) * c0;
    }

    unsigned short ob[8];
    if (ROT) {
        // Bundle b = lane>>1 spans this lane (half = lane&1 -> within-bundle
        // elems [half*8, half*8+8)) and partner lane^1. Exchange halves via
        // shfl_xor; all register arrays static-indexed (selects, not dynamic
        // indices -- dynamic reg indexing spills to scratch).
        const int half = lane & 1;
        float av[8] = {a0, a1, a2, a3, a4, a5, a6, a7};
        float rown[8] = {r0.x, r0.y, r0.z, r0.w, r1.x, r1.y, r1.z, r1.w};
        float hb[16], rv[16];
#pragma unroll
        for (int j = 0; j < 8; ++j) {
            float ho = __shfl_xor(av[j], 1);
            float ro = __shfl_xor(rown[j], 1);
            hb[j]     = half ? ho      : av[j];
            hb[8 + j] = half ? av[j]   : ho;
            rv[j]     = half ? ro      : rown[j];
            rv[8 + j] = half ? rown[j] : ro;
        }
        // my output rows c = half*2 + cc; rr[cc][d] = R[b][d][c]
        float rr[2][4];
#pragma unroll
        for (int cc = 0; cc < 2; ++cc)
#pragma unroll
            for (int d = 0; d < 4; ++d)
                rr[cc][d] = half ? rv[d * 4 + 2 + cc] : rv[d * 4 + cc];
        // g[c][e] = sum_d R[b][d][c] * h[b][d][e]  (fp32 accumulators)
#pragma unroll
        for (int cc = 0; cc < 2; ++cc)
#pragma unroll
            for (int e = 0; e < 4; ++e) {
                float acc = 0.f;
#pragma unroll
                for (int d = 0; d < 4; ++d) acc += rr[cc][d] * hb[d * 4 + e];
                ob[cc * 4 + e] = f2bf(acc);
            }
    } else {
        ob[0] = f2bf(a0); ob[1] = f2bf(a1); ob[2] = f2bf(a2); ob[3] = f2bf(a3);
        ob[4] = f2bf(a4); ob[5] = f2bf(a5); ob[6] = f2bf(a6); ob[7] = f2bf(a7);
    }
    uint4 o;
    o.x = (unsigned)ob[0] | ((unsigned)ob[1] << 16);
    o.y = (unsigned)ob[2] | ((unsigned)ob[3] << 16);
    o.z = (unsigned)ob[4] | ((unsigned)ob[5] << 16);
    o.w = (unsigned)ob[6] | ((unsigned)ob[7] << 16);
    *(uint4*)&hdst[(size_t)node * DIM + lane * 8] = o;
}

// ---------------------------------------------------------------------------
// FFN via bf16 MFMA. 64 nodes/block, 256 threads. Input h is ALREADY
// inverse-rotated (gather2 epilogue). A fragments read directly from global
// inside the MFMA loop (hA is L2/L3-hot); ONE barrier total. Tail blocks
// read past hA into adjacent ws (valid memory); garbage stays in guarded
// output rows.
#define HBST 264
__global__ __launch_bounds__(256, 4) void ffn_kernel(
        const unsigned short* __restrict__ h,    // hA [N,128] bf16, pre-rotated
        const unsigned short* __restrict__ w1b,  // [256][128] bf16
        const float* __restrict__ b1,            // [256]
        const unsigned short* __restrict__ w2b,  // [128][256] bf16
        const float* __restrict__ b2,            // [128]
        float* __restrict__ out, int n) {
    __shared__ unsigned short hbuf[64 * HBST];   // 33792 B
    const int tid  = threadIdx.x;
    const int node0 = blockIdx.x * 64;
    const int wave = tid >> 6;
    const int lane = tid & 63;
    const int lr = lane & 15;   // tile row (A) / tile col (B,C)
    const int lq = lane >> 4;   // quad -> k-block / C row group

    const unsigned short* hbase = &h[(size_t)node0 * DIM];

    // ---- GEMM1: hid[64][256] = gelu(A[64,128] @ w1^T + b1), wave owns 64 cols
    f4x acc1[4][4];
#pragma unroll
    for (int mt = 0; mt < 4; ++mt)
#pragma unroll
        for (int nt = 0; nt < 4; ++nt) acc1[mt][nt] = (f4x){0.f, 0.f, 0.f, 0.f};

    const int nw = wave * 64;
#pragma unroll
    for (int ks = 0; ks < 4; ++ks) {
        const int k0 = ks * 32 + lq * 8;
        s8x af[4], bfv[4];
#pragma unroll
        for (int mt = 0; mt < 4; ++mt)
            af[mt] = *(const s8x*)&hbase[(size_t)(mt * 16 + lr) * DIM + k0];
#pragma unroll
        for (int nt = 0; nt < 4; ++nt)
            bfv[nt] = *(const s8x*)&w1b[(size_t)(nw + nt * 16 + lr) * 128 + k0];
#pragma unroll
        for (int mt = 0; mt < 4; ++mt)
#pragma unroll
            for (int nt = 0; nt < 4; ++nt)
                acc1[mt][nt] = __builtin_amdgcn_mfma_f32_16x16x32_bf16(
                    af[mt], bfv[nt], acc1[mt][nt], 0, 0, 0);
    }

    // epilogue: bias + exact gelu -> bf16 hbuf[m][n]
#pragma unroll
    for (int nt = 0; nt < 4; ++nt) {
        int nn = nw + nt * 16 + lr;
        float bias = b1[nn];
#pragma unroll
        for (int mt = 0; mt < 4; ++mt) {
#pragma unroll
            for (int r = 0; r < 4; ++r) {
                float v = acc1[mt][nt][r] + bias;
                v = 0.5f * v * (1.f + erff(v * 0.70710678118654752f));
                hbuf[(mt * 16 + lq * 4 + r) * HBST + nn] = f2bf(v);
            }
        }
    }
    __syncthreads();

    // ---- GEMM2: out[64][128] = hid[64,256] @ w2^T + b2, wave owns 32 cols
    f4x acc2[4][2];
#pragma unroll
    for (int mt = 0; mt < 4; ++mt)
#pragma unroll
        for (int nt = 0; nt < 2; ++nt) acc2[mt][nt] = (f4x){0.f, 0.f, 0.f, 0.f};

    const int nw2 = wave * 32;
#pragma unroll
    for (int ks = 0; ks < 8; ++ks) {
        const int k0 = ks * 32 + lq * 8;
        s8x af[4], bf2v[2];
#pragma unroll
        for (int mt = 0; mt < 4; ++mt)
            af[mt] = *(const s8x*)&hbuf[(mt * 16 + lr) * HBST + k0];
#pragma unroll
        for (int nt = 0; nt < 2; ++nt)
            bf2v[nt] = *(const s8x*)&w2b[(size_t)(nw2 + nt * 16 + lr) * 256 + k0];
#pragma unroll
        for (int mt = 0; mt < 4; ++mt)
#pragma unroll
            for (int nt = 0; nt < 2; ++nt)
                acc2[mt][nt] = __builtin_amdgcn_mfma_f32_16x16x32_bf16(
                    af[mt], bf2v[nt], acc2[mt][nt], 0, 0, 0);
    }
    // epilogue: bias + store fp32
#pragma unroll
    for (int nt = 0; nt < 2; ++nt) {
        int n2 = nw2 + nt * 16 + lr;
        float bias = b2[n2];
#pragma unroll
        for (int mt = 0; mt < 4; ++mt) {
#pragma unroll
            for (int r = 0; r < 4; ++r) {
                int gn = node0 + mt * 16 + lq * 4 + r;
                if (gn < n) out[(size_t)gn * DIM + n2] = acc2[mt][nt][r] + bias;
            }
        }
    }
}

// ---------------------------------------------------------------------------
extern "C" void kernel_launch(void* const* d_in, const int* in_sizes, int n_in,
                              void* d_out, int out_size, void* d_ws, size_t ws_size,
                              hipStream_t stream) {
    const float* x   = (const float*)d_in[0];
    const float* R   = (const float*)d_in[1];
    const int*   src = (const int*)d_in[2];
    const int*   dst = (const int*)d_in[3];
    const float* w1  = (const float*)d_in[4];
    const float* b1  = (const float*)d_in[5];
    const float* w2  = (const float*)d_in[6];
    const float* b2  = (const float*)d_in[7];
    float* out = (float*)d_out;

    const int N = in_sizes[0] / DIM;   // 100000
    const int E = in_sizes[2];         // 1600000

    const int nbuck = (N + 127) >> 7;          // 782
    const int NBE = 256;                       // edge-chunk blocks (r3 best)
    const int chunk = (E + NBE - 1) / NBE;
    const int nScan = nbuck * NBE;
    const int nScan2 = 2 * nScan;              // TD+TS concatenated
    const int nbScan2 = (nScan2 + 1023) / 1024;   // 391 <= 2048 (scan_sums cap)
    const int nP = 512 * nbuck;                // degree-bin table size
    const int nbScanP = (nP + 1023) / 1024;    // 392 <= 2048

    // ws layout:
    // hA | hM (hM aliased by pairs u32[E] + sbyte u8[E] scratch)
    // edge region: ecsr uint2[E] (PACK) or esrcA int[E]
    // rdeg f32[N] | rowstart i32[N+1] | TD i32[nScan] | TS i32[nScan] |
    // bsums i32[2048] | TP i32[nP] | perm i32[N] | w1b | w2b
    unsigned short* hA = (unsigned short*)d_ws;
    unsigned short* hM = hA + (size_t)N * DIM;
    unsigned int*  pairs = (unsigned int*)hM;              // scratch in hM
    unsigned char* sbyte = (unsigned char*)(pairs + E);    // scratch in hM
    char* edge_base = (char*)(hM + (size_t)N * DIM);

    const size_t tail_bytes = (size_t)N * 4 + (size_t)(N + 1) * 4 +
                              (size_t)nScan * 8 + 2048 * 4 +
                              (size_t)nP * 4 + (size_t)N * 4 +
                              (size_t)2 * 32768 * 2;
    const size_t fixed_bytes = (size_t)N * DIM * 4;        // hA + hM
    const bool use_pack = (fixed_bytes + (size_t)E * 8 + tail_bytes) <= ws_size;
    const size_t edge_bytes = use_pack ? (size_t)E * 8 : (size_t)E * 4;

    uint2* ecsr  = (uint2*)edge_base;
    int*   esrcA = (int*)edge_base;
    char* q = edge_base + edge_bytes;
    float* rdeg     = (float*)q;
    int*   rowstart = (int*)(rdeg + N);
    int*   TD       = rowstart + (N + 1);
    int*   TS       = TD + nScan;              // contiguous after TD (fused scan)
    int*   bsums    = TS + nScan;
    int*   TP       = bsums + 2048;
    int*   perm     = TP + nP;
    unsigned short* w1b = (unsigned short*)(perm + N);
    unsigned short* w2b = w1b + 32768;

    const int BLK = 256;

    // 1) CSR hist + forward rotation + weight cvt, ONE launch
    const int nbRot = ((size_t)N * 8 + BLK - 1) / BLK;     // 3125
    hist_rot_kernel<<<NBE + nbRot + 16, BLK, 0, stream>>>(
        src, dst, TD, TS, E, nbuck, chunk, NBE,
        x, R, hA, w1, w2, w1b, w2b, N, nbRot);

    // 2) scans + scatter + finalize (bucketed counting sort, no global atomics)
    scan_blocks<<<nbScan2, BLK, 0, stream>>>(TD, TD, bsums, nScan2);
    scan_sums<<<1, BLK, 0, stream>>>(bsums, nbScan2);
    scan_add<<<(nScan2 + BLK - 1) / BLK, BLK, 0, stream>>>(TD, bsums, nScan2, nScan, E);
    scatter_edges<<<NBE, BLK, 0, stream>>>(src, dst, TD, TS, pairs, sbyte, E, nbuck, chunk, NBE);
    finalize_src<<<nbuck, BLK, 0, stream>>>(sbyte, TS, rdeg, E, nbuck, N, NBE);
    if (use_pack)
        finalize_dst<true><<<nbuck, BLK, 0, stream>>>(pairs, TD, rdeg, rowstart,
                                                      ecsr, esrcA, TP, E, nbuck, N, NBE);
    else
        finalize_dst<false><<<nbuck, BLK, 0, stream>>>(pairs, TD, rdeg, rowstart,
                                                       ecsr, esrcA, TP, E, nbuck, N, NBE);

    // 2b) degree-balancing permutation (counting sort over 512 degree bins)
    scan_blocks<<<nbScanP, BLK, 0, stream>>>(TP, TP, bsums, nP);
    scan_sums<<<1, BLK, 0, stream>>>(bsums, nbScanP);
    scan_add<<<(nP + BLK - 1) / BLK, BLK, 0, stream>>>(TP, bsums, nP, nP, 0);
    perm_scatter<<<nbuck, BLK, 0, stream>>>(rowstart, TP, perm, nbuck, N);

    // 3) gather round 1 (plain) + gather round 2 (fused inverse rotation),
    //    both in degree-sorted node order
    const int nbG = (N + 15) / 16;
    if (use_pack) {
        gather_kernel<true , false><<<nbG, BLK, 0, stream>>>(hA, ecsr, esrcA, rdeg,
                                                             rowstart, R, perm, hM, N);
        gather_kernel<true , true ><<<nbG, BLK, 0, stream>>>(hM, ecsr, esrcA, rdeg,
                                                             rowstart, R, perm, hA, N);
    } else {
        gather_kernel<false, false><<<nbG, BLK, 0, stream>>>(hA, ecsr, esrcA, rdeg,
                                                             rowstart, R, perm, hM, N);
        gather_kernel<false, true ><<<nbG, BLK, 0, stream>>>(hM, ecsr, esrcA, rdeg,
                                                             rowstart, R, perm, hA, N);
    }

    // 4) FFN (bf16 MFMA, A direct-from-global, pre-rotated input) -> out
    ffn_kernel<<<(N + 63) / 64, BLK, 0, stream>>>(hA, w1b, b1, w2b, b2, out, N);
}

// Round 10
// 414.090 us; speedup vs baseline: 1.0530x; 1.0530x over previous
//
#include <hip/hip_runtime.h>
#include <hip/hip_bf16.h>
#include <math.h>

#define DIM 128
#define HID 256

typedef short s8x __attribute__((ext_vector_type(8)));   // 8 bf16 (as raw shorts)
typedef float f4x __attribute__((ext_vector_type(4)));   // MFMA accumulator
typedef unsigned int u4x __attribute__((ext_vector_type(4)));

__device__ __forceinline__ unsigned short f2bf(float f) {
    unsigned int u = __float_as_uint(f);
    u += 0x7FFF + ((u >> 16) & 1);   // round-to-nearest-even
    return (unsigned short)(u >> 16);
}
__device__ __forceinline__ float bf2f(unsigned short b) {
    return __uint_as_float(((unsigned int)b) << 16);
}
__device__ __forceinline__ float bflo(unsigned int p) {   // low bf16 of packed pair
    return __uint_as_float(p << 16);
}
__device__ __forceinline__ float bfhi(unsigned int p) {   // high bf16 of packed pair
    return __uint_as_float(p & 0xffff0000u);
}

// ===========================================================================
// CSR build via bucketed counting sort — ZERO device-scope atomics (each costs
// ~64B HBM-side traffic on gfx950; measured 120us for one count pass in r2).
// Buckets: node id >> 7 (128 nodes/bucket). NBE=256 edge-chunk blocks.
//
// Session lessons pinned:
//  r2: global atomics per edge = ~64B HBM traffic each -> never per-edge.
//  r4: ffn occupancy 30->49% did NOT help (latency not residency bound).
//  r5: cross-barrier register prefetch in ffn -> scratch spills.
//  r6: merging independent latency-bound + streaming grids (hist+rot) wins.
//  r7: inverse rotation lives in gather2 epilogue (one fewer bf16 rounding).
//  r8: gather unroll x8 neutral-to-worse (VGPR 52, occ 36%) -> x4.
//  r9: degree-balanced perm REGRESSED (+2us gather, +10us dispatches; lost
//      edge-array inter-wave locality, FETCH 209->218MB). Gather is at its
//      random-access fabric floor (~3.5TB/s on 8x-XCD-replicated rows) —
//      occupancy 36-61%, unroll 4-8, sorted/unsorted all land 67-70us.
//  r10 (this): revert to r8 pipeline + r7 gather (x4, no perm); add
//      non-temporal stores for write-once streams (gather out rows, ffn out).
// ===========================================================================

// merged: hist blocks [0,NBE) + forward-rotation blocks [NBE,NBE+nbRot) +
// weight-cvt blocks [NBE+nbRot, NBE+nbRot+16).
__global__ __launch_bounds__(256) void hist_rot_kernel(
        const int* __restrict__ src, const int* __restrict__ dst,
        int* __restrict__ TD, int* __restrict__ TS, int nE, int nbuck, int chunk,
        int NBE,
        const float* __restrict__ x, const float* __restrict__ R,
        unsigned short* __restrict__ h0,
        const float* __restrict__ w1, const float* __restrict__ w2,
        unsigned short* __restrict__ w1b, unsigned short* __restrict__ w2b,
        int n, int nbRot) {
    __shared__ int hd[1024], hs[1024];
    const int tid = threadIdx.x, blk = blockIdx.x;

    if (blk >= NBE) {
        const int rb = blk - NBE;
        if (rb >= nbRot) {           // ---- weight conversion tail (16 blocks)
            int t = (rb - nbRot) * 256 + tid;
            for (int i = t; i < 32768; i += 4096) {
                w1b[i] = f2bf(w1[i]);
                w2b[i] = f2bf(w2[i]);
            }
            return;
        }
        // ---- forward rotation: h0 = rot(x) in bf16
        int u = rb * 256 + tid;
        if (u >= n * 8) return;
        int nd = u >> 3, b = u & 7;
        const float* xp = &x[(size_t)nd * DIM + b * 16];
        const float* Rp = &R[(size_t)nd * DIM + b * 16];
        float xv[16], rv[16];
#pragma unroll
        for (int d = 0; d < 4; ++d) {
            *(float4*)&xv[d * 4] = *(const float4*)&xp[d * 4];
            *(float4*)&rv[d * 4] = *(const float4*)&Rp[d * 4];
        }
        unsigned short ob[16];
#pragma unroll
        for (int c = 0; c < 4; ++c)
#pragma unroll
            for (int e = 0; e < 4; ++e) {
                float acc = 0.f;
#pragma unroll
                for (int d = 0; d < 4; ++d) acc += rv[c * 4 + d] * xv[d * 4 + e];
                ob[c * 4 + e] = f2bf(acc);
            }
        unsigned short* op = &h0[(size_t)nd * DIM + b * 16];
        *(s8x*)&op[0] = *(s8x*)&ob[0];
        *(s8x*)&op[8] = *(s8x*)&ob[8];
        return;
    }

    // ---- hist part: per-(block,bucket) histograms of dst and src, unroll x2
    for (int b = tid; b < nbuck; b += 256) { hd[b] = 0; hs[b] = 0; }
    __syncthreads();
    int beg = blk * chunk, end = min(beg + chunk, nE);
    int i = beg + tid;
    for (; i + 256 < end; i += 512) {
        int d0 = dst[i], d1 = dst[i + 256];
        int s0 = src[i], s1 = src[i + 256];
        atomicAdd(&hd[d0 >> 7], 1);
        atomicAdd(&hd[d1 >> 7], 1);
        atomicAdd(&hs[s0 >> 7], 1);
        atomicAdd(&hs[s1 >> 7], 1);
    }
    if (i < end) {
        atomicAdd(&hd[dst[i] >> 7], 1);
        atomicAdd(&hs[src[i] >> 7], 1);
    }
    __syncthreads();
    for (int b = tid; b < nbuck; b += 256) {   // bucket-major layout for scan
        TD[b * NBE + blk] = hd[b];
        TS[b * NBE + blk] = hs[b];
    }
}

// hierarchical exclusive scan: 1024 elems/block
__global__ void scan_blocks(const int* in, int* out, int* bsums, int n) {
    __shared__ int part[256];
    const int tid = threadIdx.x;
    const int base = blockIdx.x * 1024 + tid * 4;
    int v[4];
    int sum = 0;
#pragma unroll
    for (int k = 0; k < 4; ++k) {
        v[k] = (base + k < n) ? in[base + k] : 0;
        sum += v[k];
    }
    part[tid] = sum;
    __syncthreads();
    for (int off = 1; off < 256; off <<= 1) {
        int t = (tid >= off) ? part[tid - off] : 0;
        __syncthreads();
        part[tid] += t;
        __syncthreads();
    }
    int excl = part[tid] - sum;
    if (tid == 255) bsums[blockIdx.x] = part[255];
#pragma unroll
    for (int k = 0; k < 4; ++k) {
        if (base + k < n) out[base + k] = excl;
        excl += v[k];
    }
}

// scan of block sums, nb <= 2048, single block of 256 (8 elems/thread)
__global__ void scan_sums(int* bsums, int nb) {
    __shared__ int part[256];
    const int tid = threadIdx.x;
    const int base = tid * 8;
    int v[8];
    int sum = 0;
#pragma unroll
    for (int k = 0; k < 8; ++k) {
        v[k] = (base + k < nb) ? bsums[base + k] : 0;
        sum += v[k];
    }
    part[tid] = sum;
    __syncthreads();
    for (int off = 1; off < 256; off <<= 1) {
        int t = (tid >= off) ? part[tid - off] : 0;
        __syncthreads();
        part[tid] += t;
        __syncthreads();
    }
    int excl = part[tid] - sum;
#pragma unroll
    for (int k = 0; k < 8; ++k) {
        if (base + k < nb) bsums[base + k] = excl;
        excl += v[k];
    }
}

// add block offsets; second half (TS region) additionally corrected by -E
__global__ void scan_add(int* T, const int* __restrict__ bsums, int n2, int half, int E) {
    int i = blockIdx.x * blockDim.x + threadIdx.x;
    if (i < n2) {
        int v = T[i] + bsums[i >> 10];
        T[i] = (i >= half) ? v - E : v;
    }
}

// pass 2: scatter edges into bucket-ordered arrays using LDS cursors, unroll x2
__global__ __launch_bounds__(256) void scatter_edges(
        const int* __restrict__ src, const int* __restrict__ dst,
        const int* __restrict__ TD, const int* __restrict__ TS,
        unsigned int* __restrict__ pairs, unsigned char* __restrict__ sbyte,
        int nE, int nbuck, int chunk, int NBE) {
    __shared__ int cd[1024], cs[1024];
    const int tid = threadIdx.x, blk = blockIdx.x;
    for (int b = tid; b < nbuck; b += 256) {
        cd[b] = TD[b * NBE + blk];
        cs[b] = TS[b * NBE + blk];
    }
    __syncthreads();
    int beg = blk * chunk, end = min(beg + chunk, nE);
    int i = beg + tid;
    for (; i + 256 < end; i += 512) {
        int s0 = src[i], d0 = dst[i];
        int s1 = src[i + 256], d1 = dst[i + 256];
        int pd0 = atomicAdd(&cd[d0 >> 7], 1);
        pairs[pd0] = ((unsigned)s0 << 7) | (unsigned)(d0 & 127);
        int pd1 = atomicAdd(&cd[d1 >> 7], 1);
        pairs[pd1] = ((unsigned)s1 << 7) | (unsigned)(d1 & 127);
        int ps0 = atomicAdd(&cs[s0 >> 7], 1);
        sbyte[ps0] = (unsigned char)(s0 & 127);
        int ps1 = atomicAdd(&cs[s1 >> 7], 1);
        sbyte[ps1] = (unsigned char)(s1 & 127);
    }
    if (i < end) {
        int s = src[i], d = dst[i];
        int pd = atomicAdd(&cd[d >> 7], 1);
        pairs[pd] = ((unsigned)s << 7) | (unsigned)(d & 127);
        int ps = atomicAdd(&cs[s >> 7], 1);
        sbyte[ps] = (unsigned char)(s & 127);
    }
}

// pass 3a: per src-bucket out-degree histogram -> rdeg = rsqrt(deg)
__global__ __launch_bounds__(256) void finalize_src(
        const unsigned char* __restrict__ sbyte, const int* __restrict__ TS,
        float* __restrict__ rdeg, int nE, int nbuck, int nN, int NBE) {
    __shared__ int hist[128];
    const int tid = threadIdx.x, b = blockIdx.x;
    if (tid < 128) hist[tid] = 0;
    __syncthreads();
    int beg = TS[b * NBE];
    int end = (b + 1 < nbuck) ? TS[(b + 1) * NBE] : nE;
    for (int i = beg + tid; i < end; i += 256)
        atomicAdd(&hist[sbyte[i]], 1);
    __syncthreads();
    if (tid < 128) {
        int idx = (b << 7) + tid;
        if (idx < nN) rdeg[idx] = rsqrtf((float)hist[tid]);
    }
}

// pass 3b: per dst-bucket finalize: rowstart + locally sorted (src,coef)
template<bool PACK>
__global__ __launch_bounds__(256) void finalize_dst(
        const unsigned int* __restrict__ pairs, const int* __restrict__ TD,
        const float* __restrict__ rdeg,
        int* __restrict__ rowstart, uint2* __restrict__ ecsr,
        int* __restrict__ esrcA, int nE, int nbuck, int nN, int NBE) {
    __shared__ int hist[128], sbuf[128], cur[128];
    const int tid = threadIdx.x, b = blockIdx.x;
    int beg = TD[b * NBE];
    int end = (b + 1 < nbuck) ? TD[(b + 1) * NBE] : nE;
    if (tid < 128) hist[tid] = 0;
    __syncthreads();
    for (int i = beg + tid; i < end; i += 256)
        atomicAdd(&hist[(int)(pairs[i] & 127u)], 1);
    __syncthreads();
    int v = (tid < 128) ? hist[tid] : 0;
    if (tid < 128) sbuf[tid] = v;
    __syncthreads();
    for (int off = 1; off < 128; off <<= 1) {
        int t = (tid < 128 && tid >= off) ? sbuf[tid - off] : 0;
        __syncthreads();
        if (tid < 128) sbuf[tid] += t;
        __syncthreads();
    }
    if (tid < 128) {
        int excl = sbuf[tid] - v;
        cur[tid] = excl;
        int idx = (b << 7) + tid;
        if (idx <= nN) rowstart[idx] = beg + excl;   // covers rowstart[N]=E too
    }
    __syncthreads();
    for (int i = beg + tid; i < end; i += 256) {
        unsigned int p = pairs[i];
        int l = (int)(p & 127u);
        int s = (int)(p >> 7);
        int pos = atomicAdd(&cur[l], 1);
        if (PACK) {
            float coef = rdeg[s] * rdeg[(b << 7) + l];
            ecsr[beg + pos] = make_uint2((unsigned)s, __float_as_uint(coef));
        } else {
            esrcA[beg + pos] = s;
        }
    }
}

// ---------------------------------------------------------------------------
// gather round (bf16 rows): hdst[v] = sum_{e in row v} hsrc[esrc[e]] * coef
// 16 lanes per node (16 B dwordx4 each), 16 nodes per 256-block, unroll x4
// (x8: neutral-worse r8; degree-sorted perm: worse r9). Output row stored
// non-temporally (write-once stream; keeps L2 for the hot row-set).
// Template ROT: round-2 variant applies the inverse rotation R^T per bundle
// to the fp32 accumulators before the bf16 write.
template<bool PACK, bool ROT>
__global__ __launch_bounds__(256) void gather_kernel(
        const unsigned short* __restrict__ hsrc,
        const uint2* __restrict__ ecsr, const int* __restrict__ esrcA,
        const float* __restrict__ rdeg, const int* __restrict__ rowstart,
        const float* __restrict__ R,
        unsigned short* __restrict__ hdst, int n) {
    const int node = blockIdx.x * 16 + (threadIdx.x >> 4);
    const int lane = threadIdx.x & 15;        // owns 8 bf16 = 16 B of the row
    if (node >= n) return;
    const int beg = rowstart[node];
    const int end = rowstart[node + 1];
    float rd = 0.f;
    if (!PACK) rd = rdeg[node];

    // issue R row load early (ROT only): lane owns floats [lane*8, lane*8+8)
    float4 r0, r1;
    if (ROT) {
        r0 = *(const float4*)&R[(size_t)node * DIM + lane * 8];
        r1 = *(const float4*)&R[(size_t)node * DIM + lane * 8 + 4];
    }

    float a0 = 0.f, a1 = 0.f, a2 = 0.f, a3 = 0.f;
    float a4 = 0.f, a5 = 0.f, a6 = 0.f, a7 = 0.f;
    int i = beg;
    for (; i + 4 <= end; i += 4) {
        int s0, s1, s2, s3;
        float c0, c1, c2, c3;
        if (PACK) {
            uint2 e0 = ecsr[i], e1 = ecsr[i + 1], e2 = ecsr[i + 2], e3 = ecsr[i + 3];
            s0 = (int)e0.x; c0 = __uint_as_float(e0.y);
            s1 = (int)e1.x; c1 = __uint_as_float(e1.y);
            s2 = (int)e2.x; c2 = __uint_as_float(e2.y);
            s3 = (int)e3.x; c3 = __uint_as_float(e3.y);
        } else {
            s0 = esrcA[i]; s1 = esrcA[i + 1]; s2 = esrcA[i + 2]; s3 = esrcA[i + 3];
            c0 = rdeg[s0] * rd; c1 = rdeg[s1] * rd;
            c2 = rdeg[s2] * rd; c3 = rdeg[s3] * rd;
        }
        uint4 p0 = *(const uint4*)&hsrc[(size_t)s0 * DIM + lane * 8];
        uint4 p1 = *(const uint4*)&hsrc[(size_t)s1 * DIM + lane * 8];
        uint4 p2 = *(const uint4*)&hsrc[(size_t)s2 * DIM + lane * 8];
        uint4 p3 = *(const uint4*)&hsrc[(size_t)s3 * DIM + lane * 8];
        a0 += bflo(p0.x) * c0 + bflo(p1.x) * c1 + bflo(p2.x) * c2 + bflo(p3.x) * c3;
        a1 += bfhi(p0.x) * c0 + bfhi(p1.x) * c1 + bfhi(p2.x) * c2 + bfhi(p3.x) * c3;
        a2 += bflo(p0.y) * c0 + bflo(p1.y) * c1 + bflo(p2.y) * c2 + bflo(p3.y) * c3;
        a3 += bfhi(p0.y) * c0 + bfhi(p1.y) * c1 + bfhi(p2.y) * c2 + bfhi(p3.y) * c3;
        a4 += bflo(p0.z) * c0 + bflo(p1.z) * c1 + bflo(p2.z) * c2 + bflo(p3.z) * c3;
        a5 += bfhi(p0.z) * c0 + bfhi(p1.z) * c1 + bfhi(p2.z) * c2 + bfhi(p3.z) * c3;
        a6 += bflo(p0.w) * c0 + bflo(p1.w) * c1 + bflo(p2.w) * c2 + bflo(p3.w) * c3;
        a7 += bfhi(p0.w) * c0 + bfhi(p1.w) * c1 + bfhi(p2.w) * c2 + bfhi(p3.w) * c3;
    }
    for (; i < end; ++i) {
        int s0;
        float c0;
        if (PACK) {
            uint2 e0 = ecsr[i];
            s0 = (int)e0.x; c0 = __uint_as_float(e0.y);
        } else {
            s0 = esrcA[i];
            c0 = rdeg[s0] * rd;
        }
        uint4 p0 = *(const uint4*)&hsrc[(size_t)s0 * DIM + lane * 8];
        a0 += bflo(p0.x) * c0;
        a1 += bfhi(p0.x) * c0;
        a2 += bflo(p0.y) * c0;
        a3 += bfhi(p0.y) * c0;
        a4 += bflo(p0.z) * c0;
        a5 += bfhi(p0.z) * c0;
        a6 += bflo(p0.w) * c0;
        a7 += bfhi(p0.w) * c0;
    }

    unsigned short ob[8];
    if (ROT) {
        // Bundle b = lane>>1 spans this lane (half = lane&1 -> within-bundle
        // elems [half*8, half*8+8)) and partner lane^1. Exchange halves via
        // shfl_xor; all register arrays static-indexed (selects, not dynamic
        // indices -- dynamic reg indexing spills to scratch).
        const int half = lane & 1;
        float av[8] = {a0, a1, a2, a3, a4, a5, a6, a7};
        float rown[8] = {r0.x, r0.y, r0.z, r0.w, r1.x, r1.y, r1.z, r1.w};
        float hb[16], rv[16];
#pragma unroll
        for (int j = 0; j < 8; ++j) {
            float ho = __shfl_xor(av[j], 1);
            float ro = __shfl_xor(rown[j], 1);
            hb[j]     = half ? ho      : av[j];
            hb[8 + j] = half ? av[j]   : ho;
            rv[j]     = half ? ro      : rown[j];
            rv[8 + j] = half ? rown[j] : ro;
        }
        // my output rows c = half*2 + cc; rr[cc][d] = R[b][d][c]
        float rr[2][4];
#pragma unroll
        for (int cc = 0; cc < 2; ++cc)
#pragma unroll
            for (int d = 0; d < 4; ++d)
                rr[cc][d] = half ? rv[d * 4 + 2 + cc] : rv[d * 4 + cc];
        // g[c][e] = sum_d R[b][d][c] * h[b][d][e]  (fp32 accumulators)
#pragma unroll
        for (int cc = 0; cc < 2; ++cc)
#pragma unroll
            for (int e = 0; e < 4; ++e) {
                float acc = 0.f;
#pragma unroll
                for (int d = 0; d < 4; ++d) acc += rr[cc][d] * hb[d * 4 + e];
                ob[cc * 4 + e] = f2bf(acc);
            }
    } else {
        ob[0] = f2bf(a0); ob[1] = f2bf(a1); ob[2] = f2bf(a2); ob[3] = f2bf(a3);
        ob[4] = f2bf(a4); ob[5] = f2bf(a5); ob[6] = f2bf(a6); ob[7] = f2bf(a7);
    }
    u4x o;
    o.x = (unsigned)ob[0] | ((unsigned)ob[1] << 16);
    o.y = (unsigned)ob[2] | ((unsigned)ob[3] << 16);
    o.z = (unsigned)ob[4] | ((unsigned)ob[5] << 16);
    o.w = (unsigned)ob[6] | ((unsigned)ob[7] << 16);
    __builtin_nontemporal_store(o, (u4x*)&hdst[(size_t)node * DIM + lane * 8]);
}

// ---------------------------------------------------------------------------
// FFN via bf16 MFMA. 64 nodes/block, 256 threads. Input h is ALREADY
// inverse-rotated (gather2 epilogue). A fragments read directly from global
// inside the MFMA loop (hA is L2/L3-hot); ONE barrier total. Output stored
// non-temporally (write-once fp32 stream). Tail blocks read past hA into
// adjacent ws (valid memory); garbage stays in guarded output rows.
#define HBST 264
__global__ __launch_bounds__(256, 4) void ffn_kernel(
        const unsigned short* __restrict__ h,    // hA [N,128] bf16, pre-rotated
        const unsigned short* __restrict__ w1b,  // [256][128] bf16
        const float* __restrict__ b1,            // [256]
        const unsigned short* __restrict__ w2b,  // [128][256] bf16
        const float* __restrict__ b2,            // [128]
        float* __restrict__ out, int n) {
    __shared__ unsigned short hbuf[64 * HBST];   // 33792 B
    const int tid  = threadIdx.x;
    const int node0 = blockIdx.x * 64;
    const int wave = tid >> 6;
    const int lane = tid & 63;
    const int lr = lane & 15;   // tile row (A) / tile col (B,C)
    const int lq = lane >> 4;   // quad -> k-block / C row group

    const unsigned short* hbase = &h[(size_t)node0 * DIM];

    // ---- GEMM1: hid[64][256] = gelu(A[64,128] @ w1^T + b1), wave owns 64 cols
    f4x acc1[4][4];
#pragma unroll
    for (int mt = 0; mt < 4; ++mt)
#pragma unroll
        for (int nt = 0; nt < 4; ++nt) acc1[mt][nt] = (f4x){0.f, 0.f, 0.f, 0.f};

    const int nw = wave * 64;
#pragma unroll
    for (int ks = 0; ks < 4; ++ks) {
        const int k0 = ks * 32 + lq * 8;
        s8x af[4], bfv[4];
#pragma unroll
        for (int mt = 0; mt < 4; ++mt)
            af[mt] = *(const s8x*)&hbase[(size_t)(mt * 16 + lr) * DIM + k0];
#pragma unroll
        for (int nt = 0; nt < 4; ++nt)
            bfv[nt] = *(const s8x*)&w1b[(size_t)(nw + nt * 16 + lr) * 128 + k0];
#pragma unroll
        for (int mt = 0; mt < 4; ++mt)
#pragma unroll
            for (int nt = 0; nt < 4; ++nt)
                acc1[mt][nt] = __builtin_amdgcn_mfma_f32_16x16x32_bf16(
                    af[mt], bfv[nt], acc1[mt][nt], 0, 0, 0);
    }

    // epilogue: bias + exact gelu -> bf16 hbuf[m][n]
#pragma unroll
    for (int nt = 0; nt < 4; ++nt) {
        int nn = nw + nt * 16 + lr;
        float bias = b1[nn];
#pragma unroll
        for (int mt = 0; mt < 4; ++mt) {
#pragma unroll
            for (int r = 0; r < 4; ++r) {
                float v = acc1[mt][nt][r] + bias;
                v = 0.5f * v * (1.f + erff(v * 0.70710678118654752f));
                hbuf[(mt * 16 + lq * 4 + r) * HBST + nn] = f2bf(v);
            }
        }
    }
    __syncthreads();

    // ---- GEMM2: out[64][128] = hid[64,256] @ w2^T + b2, wave owns 32 cols
    f4x acc2[4][2];
#pragma unroll
    for (int mt = 0; mt < 4; ++mt)
#pragma unroll
        for (int nt = 0; nt < 2; ++nt) acc2[mt][nt] = (f4x){0.f, 0.f, 0.f, 0.f};

    const int nw2 = wave * 32;
#pragma unroll
    for (int ks = 0; ks < 8; ++ks) {
        const int k0 = ks * 32 + lq * 8;
        s8x af[4], bf2v[2];
#pragma unroll
        for (int mt = 0; mt < 4; ++mt)
            af[mt] = *(const s8x*)&hbuf[(mt * 16 + lr) * HBST + k0];
#pragma unroll
        for (int nt = 0; nt < 2; ++nt)
            bf2v[nt] = *(const s8x*)&w2b[(size_t)(nw2 + nt * 16 + lr) * 256 + k0];
#pragma unroll
        for (int mt = 0; mt < 4; ++mt)
#pragma unroll
            for (int nt = 0; nt < 2; ++nt)
                acc2[mt][nt] = __builtin_amdgcn_mfma_f32_16x16x32_bf16(
                    af[mt], bf2v[nt], acc2[mt][nt], 0, 0, 0);
    }
    // epilogue: bias + store fp32 (non-temporal: never re-read)
#pragma unroll
    for (int nt = 0; nt < 2; ++nt) {
        int n2 = nw2 + nt * 16 + lr;
        float bias = b2[n2];
#pragma unroll
        for (int mt = 0; mt < 4; ++mt) {
#pragma unroll
            for (int r = 0; r < 4; ++r) {
                int gn = node0 + mt * 16 + lq * 4 + r;
                if (gn < n)
                    __builtin_nontemporal_store(acc2[mt][nt][r] + bias,
                                                &out[(size_t)gn * DIM + n2]);
            }
        }
    }
}

// ---------------------------------------------------------------------------
extern "C" void kernel_launch(void* const* d_in, const int* in_sizes, int n_in,
                              void* d_out, int out_size, void* d_ws, size_t ws_size,
                              hipStream_t stream) {
    const float* x   = (const float*)d_in[0];
    const float* R   = (const float*)d_in[1];
    const int*   src = (const int*)d_in[2];
    const int*   dst = (const int*)d_in[3];
    const float* w1  = (const float*)d_in[4];
    const float* b1  = (const float*)d_in[5];
    const float* w2  = (const float*)d_in[6];
    const float* b2  = (const float*)d_in[7];
    float* out = (float*)d_out;

    const int N = in_sizes[0] / DIM;   // 100000
    const int E = in_sizes[2];         // 1600000

    const int nbuck = (N + 127) >> 7;          // 782
    const int NBE = 256;                       // edge-chunk blocks (r3 best)
    const int chunk = (E + NBE - 1) / NBE;
    const int nScan = nbuck * NBE;
    const int nScan2 = 2 * nScan;              // TD+TS concatenated
    const int nbScan2 = (nScan2 + 1023) / 1024;   // 391 <= 2048 (scan_sums cap)

    // ws layout:
    // hA [N*128 bf16] | hM [N*128 bf16]  (hM aliased by pairs u32[E] + sbyte u8[E],
    //   both dead before gather1 writes hM)
    // edge region: ecsr uint2[E] (PACK) or esrcA int[E] (fallback)
    // rdeg f32[N] | rowstart i32[N+1] | TD i32[nScan] | TS i32[nScan] |
    // bsums i32[2048] | w1b us[32768] | w2b us[32768]
    unsigned short* hA = (unsigned short*)d_ws;
    unsigned short* hM = hA + (size_t)N * DIM;
    unsigned int*  pairs = (unsigned int*)hM;              // scratch in hM
    unsigned char* sbyte = (unsigned char*)(pairs + E);    // scratch in hM
    char* edge_base = (char*)(hM + (size_t)N * DIM);

    const size_t tail_bytes = (size_t)N * 4 + (size_t)(N + 1) * 4 +
                              (size_t)nScan * 8 + 2048 * 4 + (size_t)2 * 32768 * 2;
    const size_t fixed_bytes = (size_t)N * DIM * 4;        // hA + hM
    const bool use_pack = (fixed_bytes + (size_t)E * 8 + tail_bytes) <= ws_size;
    const size_t edge_bytes = use_pack ? (size_t)E * 8 : (size_t)E * 4;

    uint2* ecsr  = (uint2*)edge_base;
    int*   esrcA = (int*)edge_base;
    char* q = edge_base + edge_bytes;
    float* rdeg     = (float*)q;
    int*   rowstart = (int*)(rdeg + N);
    int*   TD       = rowstart + (N + 1);
    int*   TS       = TD + nScan;              // contiguous after TD (fused scan)
    int*   bsums    = TS + nScan;
    unsigned short* w1b = (unsigned short*)(bsums + 2048);
    unsigned short* w2b = w1b + 32768;

    const int BLK = 256;

    // 1) CSR hist + forward rotation + weight cvt, ONE launch
    const int nbRot = ((size_t)N * 8 + BLK - 1) / BLK;     // 3125
    hist_rot_kernel<<<NBE + nbRot + 16, BLK, 0, stream>>>(
        src, dst, TD, TS, E, nbuck, chunk, NBE,
        x, R, hA, w1, w2, w1b, w2b, N, nbRot);

    // 2) scans + scatter + finalize (bucketed counting sort, no global atomics)
    scan_blocks<<<nbScan2, BLK, 0, stream>>>(TD, TD, bsums, nScan2);
    scan_sums<<<1, BLK, 0, stream>>>(bsums, nbScan2);
    scan_add<<<(nScan2 + BLK - 1) / BLK, BLK, 0, stream>>>(TD, bsums, nScan2, nScan, E);
    scatter_edges<<<NBE, BLK, 0, stream>>>(src, dst, TD, TS, pairs, sbyte, E, nbuck, chunk, NBE);
    finalize_src<<<nbuck, BLK, 0, stream>>>(sbyte, TS, rdeg, E, nbuck, N, NBE);
    if (use_pack)
        finalize_dst<true><<<nbuck, BLK, 0, stream>>>(pairs, TD, rdeg, rowstart,
                                                      ecsr, esrcA, E, nbuck, N, NBE);
    else
        finalize_dst<false><<<nbuck, BLK, 0, stream>>>(pairs, TD, rdeg, rowstart,
                                                       ecsr, esrcA, E, nbuck, N, NBE);

    // 3) gather round 1 (plain) + gather round 2 (fused inverse rotation)
    const int nbG = (N + 15) / 16;
    if (use_pack) {
        gather_kernel<true , false><<<nbG, BLK, 0, stream>>>(hA, ecsr, esrcA, rdeg,
                                                             rowstart, R, hM, N);
        gather_kernel<true , true ><<<nbG, BLK, 0, stream>>>(hM, ecsr, esrcA, rdeg,
                                                             rowstart, R, hA, N);
    } else {
        gather_kernel<false, false><<<nbG, BLK, 0, stream>>>(hA, ecsr, esrcA, rdeg,
                                                             rowstart, R, hM, N);
        gather_kernel<false, true ><<<nbG, BLK, 0, stream>>>(hM, ecsr, esrcA, rdeg,
                                                             rowstart, R, hA, N);
    }

    // 4) FFN (bf16 MFMA, A direct-from-global, pre-rotated input) -> out
    ffn_kernel<<<(N + 63) / 64, BLK, 0, stream>>>(hA, w1b, b1, w2b, b2, out, N);
}